// Round 1
// baseline (170.535 us; speedup 1.0000x reference)
//
#include <hip/hip_runtime.h>
#include <stdint.h>
#include <stddef.h>

typedef _Float16 f16;
typedef f16 f16x4 __attribute__((ext_vector_type(4)));
typedef f16 f16x8 __attribute__((ext_vector_type(8)));
typedef float f32x4 __attribute__((ext_vector_type(4)));

#define DEV __device__ __forceinline__

constexpr int Bb = 4, Nn = 8192, Mm = 2048, C1 = 128, C2 = 256;
constexpr int K0 = 384, CO = 256;

// ---------------------------------------------------------------- 0) pack known -> float4 (kx,ky,kz,|k|^2), kk bitwise same as before
__global__ __launch_bounds__(256) void kprep_kernel(const float* __restrict__ known, float4* __restrict__ k4)
{
  int id = blockIdx.x * 256 + threadIdx.x;      // < Bb*Mm
  float kx = known[id * 3 + 0];
  float ky = known[id * 3 + 1];
  float kz = known[id * 3 + 2];
  float kk = __fadd_rn(__fadd_rn(__fmul_rn(kx, kx), __fmul_rn(ky, ky)), __fmul_rn(kz, kz));
  k4[id] = make_float4(kx, ky, kz, kk);
}

// ---------------------------------------------------------------- 1) three_nn (np-mimic fp32), query-per-lane, k-points in SGPRs
// Each lane owns one query; each wave scans a wave-uniform slice of M (2048/8 = 256 candidates).
// The candidate point is wave-uniform -> s_load_dwordx4 into SGPRs (scalar pipe; no LDS, no
// per-lane address math, scalar gm). Double-buffered 8-candidate prefetch hides SMEM latency.
// Per-pair math identical to previous verified kernel: pre-doubled query coords make
// dot2 == np's 2.0*einsum BITWISE; strict-less insertion in increasing gm + lexicographic
// (d,i) cross-wave merge reproduces numpy top_k stable tie-breaking exactly.
__global__ __launch_bounds__(512) void knn_kernel(
    const float* __restrict__ unknown, const float4* __restrict__ k4,
    int* __restrict__ oidx, float* __restrict__ ow)
{
  __shared__ float mergeD[8][64][3];   // 6 KB
  __shared__ int   mergeI[8][64][3];   // 6 KB
  const int t = threadIdx.x;
  const int l = t & 63;
  const int w = __builtin_amdgcn_readfirstlane(t >> 6);   // wave id 0..7, force SGPR
  const int bx = blockIdx.x;
  const int b  = bx >> 7;              // 128 blocks per batch
  const int n0 = (bx & 127) * 64;
  const int q  = n0 + l;

  float ux = unknown[(b * Nn + q) * 3 + 0];
  float uy = unknown[(b * Nn + q) * 3 + 1];
  float uz = unknown[(b * Nn + q) * 3 + 2];
  float uu = __fadd_rn(__fadd_rn(__fmul_rn(ux, ux), __fmul_rn(uy, uy)), __fmul_rn(uz, uz));
  float ux2 = ux + ux, uy2 = uy + uy, uz2 = uz + uz;   // exact (x2 = exponent bump)

  const float4* kb = k4 + (size_t)b * Mm + w * 256;    // wave-uniform base
  const int gmb = w * 256;

  float d1 = 1e30f, d2 = 1e30f, d3 = 1e30f;
  int   i1 = 0, i2 = 0, i3 = 0;

  float4 c[8], nx[8];
#pragma unroll
  for (int j = 0; j < 8; ++j) c[j] = kb[j];

  for (int g = 0; g < 32; ++g) {                       // 32 groups x 8 candidates
    if (g < 31) {
#pragma unroll
      for (int j = 0; j < 8; ++j) nx[j] = kb[(g + 1) * 8 + j];
    }
#pragma unroll
    for (int j = 0; j < 8; ++j) {
      float4 kp = c[j];
      int gm = gmb + g * 8 + j;                        // uniform scalar
      float dot2 = __fadd_rn(__fadd_rn(__fmul_rn(ux2, kp.x), __fmul_rn(uy2, kp.y)), __fmul_rn(uz2, kp.z));
      float dd   = __fadd_rn(__fsub_rn(uu, dot2), kp.w);  // (uu - 2*dot) + kk, np order
      bool c1 = dd < d1, c2 = dd < d2, c3 = dd < d3;
      i3 = c3 ? (c2 ? i2 : gm) : i3;
      i2 = c2 ? (c1 ? i1 : gm) : i2;
      i1 = c1 ? gm : i1;
      d3 = __builtin_amdgcn_fmed3f(dd, d2, d3);
      d2 = __builtin_amdgcn_fmed3f(dd, d1, d2);
      d1 = fminf(dd, d1);
    }
    if (g < 31) {
#pragma unroll
      for (int j = 0; j < 8; ++j) c[j] = nx[j];
    }
  }

  // per-wave partials -> LDS, then wave 0 merges 8 partials per query (ties -> lower index)
  mergeD[w][l][0] = d1; mergeD[w][l][1] = d2; mergeD[w][l][2] = d3;
  mergeI[w][l][0] = i1; mergeI[w][l][1] = i2; mergeI[w][l][2] = i3;
  __syncthreads();

  if (t < 64) {
    float e1 = mergeD[0][t][0], e2 = mergeD[0][t][1], e3 = mergeD[0][t][2];
    int   j1 = mergeI[0][t][0], j2 = mergeI[0][t][1], j3 = mergeI[0][t][2];
    d1 = e1; d2 = e2; d3 = e3; i1 = j1; i2 = j2; i3 = j3;
#pragma unroll
    for (int ww = 1; ww < 8; ++ww) {
#pragma unroll
      for (int u = 0; u < 3; ++u) {
        float e = mergeD[ww][t][u];
        int   j = mergeI[ww][t][u];
        bool c3 = (e < d3) || (e == d3 && j < i3);
        bool c2 = (e < d2) || (e == d2 && j < i2);
        bool c1 = (e < d1) || (e == d1 && j < i1);
        d3 = c3 ? (c2 ? d2 : e) : d3;  i3 = c3 ? (c2 ? i2 : j) : i3;
        d2 = c2 ? (c1 ? d1 : e) : d2;  i2 = c2 ? (c1 ? i1 : j) : i2;
        d1 = c1 ? e : d1;              i1 = c1 ? j : i1;
      }
    }
    float t1 = sqrtf(fmaxf(d1, 0.f)), t2 = sqrtf(fmaxf(d2, 0.f)), t3 = sqrtf(fmaxf(d3, 0.f));
    float r1 = 1.f / (t1 + 1e-8f), r2 = 1.f / (t2 + 1e-8f), r3 = 1.f / (t3 + 1e-8f);
    float rs = __fadd_rn(__fadd_rn(r1, r2), r3);
    int qq = n0 + t;
    int base = (b * Nn + qq) * 3;
    oidx[base + 0] = i1; oidx[base + 1] = i2; oidx[base + 2] = i3;
    ow[base + 0] = r1 / rs; ow[base + 1] = r2 / rs; ow[base + 2] = r3 / rs;
  }
}

// ---------------------------------------------------------------- 2) known_feats (B,C2,M) f32 -> kfT (B,M,C2) f16
__global__ __launch_bounds__(256) void kft_kernel(const float* __restrict__ kf, f16* __restrict__ kfT)
{
  __shared__ f16 tile[64][72];
  const int t = threadIdx.x;
  const int m0 = blockIdx.x * 64, c0 = blockIdx.y * 64, b = blockIdx.z;
  const int lm = t & 63, row = t >> 6;
#pragma unroll
  for (int j = 0; j < 16; ++j) {
    int c = row + j * 4;
    tile[lm][c] = (f16)kf[(size_t)(b * C2 + c0 + c) * Mm + m0 + lm];
  }
  __syncthreads();
#pragma unroll
  for (int j = 0; j < 16; ++j) {
    int m = row + j * 4;
    kfT[(size_t)(b * Mm + m0 + m) * C2 + c0 + lm] = tile[m][lm];
  }
}

// ---------------------------------------------------------------- 3) weights f32 -> f16 in MFMA A-fragment order
__global__ void wrep_kernel(const float* __restrict__ W0, const float* __restrict__ W1,
                            f16* __restrict__ Af0, f16* __restrict__ Af1)
{
  int id = blockIdx.x * 256 + threadIdx.x;
  if (id < CO * K0) {
    int e = id & 7, lane = (id >> 3) & 63, mg = (id >> 9) & 15, ks = id >> 13;
    int m = mg * 16 + (lane & 15), k = ks * 32 + (lane >> 4) * 8 + e;
    Af0[id] = (f16)W0[m * K0 + k];
  }
  if (id < CO * CO) {
    int e = id & 7, lane = (id >> 3) & 63, mg = (id >> 9) & 15, ks = id >> 13;
    int m = mg * 16 + (lane & 15), k = ks * 32 + (lane >> 4) * 8 + e;
    Af1[id] = (f16)W1[m * CO + k];
  }
}

// ---------------------------------------------------------------- 4) fused interp + concat + MLP0 + MLP1 (unchanged)
__global__ __launch_bounds__(256) void mlp_fused(
    const f16* __restrict__ Af0, const f16* __restrict__ Af1,
    const f16* __restrict__ kfT, const float* __restrict__ uf,
    const int* __restrict__ idx, const float* __restrict__ wts,
    const float* __restrict__ bs0, const float* __restrict__ g0,
    const float* __restrict__ be0, const float* __restrict__ rm0, const float* __restrict__ rv0,
    const float* __restrict__ bs1, const float* __restrict__ g1,
    const float* __restrict__ be1, const float* __restrict__ rm1, const float* __restrict__ rv1,
    float* __restrict__ out)
{
  __shared__ __align__(16) char lds[53248];
  const int t = threadIdx.x;
  const int w = t >> 6, l = t & 63, lm = l & 15, qq = l >> 4;
  const int gid = blockIdx.x;
  const int b = gid >> 7, n0 = (gid & 127) * 64;

  float* bn0S = (float*)(lds + 49152);
  float* bn0H = (float*)(lds + 50176);
  float* bn1S = (float*)(lds + 51200);
  float* bn1H = (float*)(lds + 52224);
  {
    float sc0 = g0[t] / sqrtf(rv0[t] + 1e-5f);
    bn0S[t] = sc0; bn0H[t] = (bs0[t] - rm0[t]) * sc0 + be0[t];
    float sc1 = g1[t] / sqrtf(rv1[t] + 1e-5f);
    bn1S[t] = sc1; bn1H[t] = (bs1[t] - rm1[t]) * sc1 + be1[t];
  }

  {
    const int n = t >> 2, kg = t & 3;
    const int base = (b * Nn + n0 + n) * 3;
    int i0 = idx[base], i1 = idx[base + 1], i2 = idx[base + 2];
    float w0 = wts[base], w1 = wts[base + 1], w2 = wts[base + 2];
    f16 w0h = (f16)w0, w1h = (f16)w1, w2h = (f16)w2;
    f16x8 w0v = {w0h, w0h, w0h, w0h, w0h, w0h, w0h, w0h};
    f16x8 w1v = {w1h, w1h, w1h, w1h, w1h, w1h, w1h, w1h};
    f16x8 w2v = {w2h, w2h, w2h, w2h, w2h, w2h, w2h, w2h};
    const f16x8* r0 = (const f16x8*)(kfT + (size_t)(b * Mm + i0) * C2 + kg * 64);
    const f16x8* r1 = (const f16x8*)(kfT + (size_t)(b * Mm + i1) * C2 + kg * 64);
    const f16x8* r2 = (const f16x8*)(kfT + (size_t)(b * Mm + i2) * C2 + kg * 64);
#pragma unroll
    for (int j = 0; j < 8; ++j) {
      f16x8 o = r0[j] * w0v + r1[j] * w1v + r2[j] * w2v;
      int oct = kg * 8 + j;
      *(f16x8*)(lds + n * 768 + ((oct ^ (n & 7)) * 16)) = o;
    }
  }
  {
    const int n = t & 63, cb = (t >> 6) * 32;
    const float* src = uf + (size_t)(b * C1 + cb) * Nn + n0 + n;
#pragma unroll
    for (int jj = 0; jj < 4; ++jj) {
      f16x8 v;
#pragma unroll
      for (int e = 0; e < 8; ++e) v[e] = (f16)src[(size_t)(jj * 8 + e) * Nn];
      int oct = 32 + (cb >> 3) + jj;
      *(f16x8*)(lds + n * 768 + ((oct ^ (n & 7)) * 16)) = v;
    }
  }
  __syncthreads();

  f32x4 acc[4][4] = {};
  {
    f16x8 af[4];
#pragma unroll
    for (int i = 0; i < 4; ++i)
      af[i] = *(const f16x8*)(Af0 + ((size_t)(w * 4 + i) * 64 + l) * 8);
    for (int ks = 0; ks < 12; ++ks) {
      f16x8 afn[4];
      if (ks < 11) {
#pragma unroll
        for (int i = 0; i < 4; ++i)
          afn[i] = *(const f16x8*)(Af0 + ((size_t)((ks + 1) * 16 + w * 4 + i) * 64 + l) * 8);
      }
      f16x8 bf[4];
#pragma unroll
      for (int j = 0; j < 4; ++j) {
        int n = j * 16 + lm;
        bf[j] = *(const f16x8*)(lds + n * 768 + (((ks * 4 + qq) ^ (n & 7)) * 16));
      }
#pragma unroll
      for (int i = 0; i < 4; ++i)
#pragma unroll
        for (int j = 0; j < 4; ++j)
          acc[i][j] = __builtin_amdgcn_mfma_f32_16x16x32_f16(af[i], bf[j], acc[i][j], 0, 0, 0);
#pragma unroll
      for (int i = 0; i < 4; ++i) af[i] = afn[i];
    }
  }
  __syncthreads();

#pragma unroll
  for (int i = 0; i < 4; ++i) {
    const int mq = w * 64 + i * 16 + qq * 4;
    f32x4 s4 = *(const f32x4*)&bn0S[mq];
    f32x4 h4 = *(const f32x4*)&bn0H[mq];
#pragma unroll
    for (int j = 0; j < 4; ++j) {
      int n = j * 16 + lm;
      f16x4 v;
#pragma unroll
      for (int r = 0; r < 4; ++r) v[r] = (f16)fmaxf(fmaf(acc[i][j][r], s4[r], h4[r]), 0.f);
      *(f16x4*)(lds + n * 512 + (((mq >> 3) ^ (n & 7)) * 16) + (mq & 7) * 2) = v;
    }
  }
  __syncthreads();

#pragma unroll
  for (int i = 0; i < 4; ++i)
#pragma unroll
    for (int j = 0; j < 4; ++j) acc[i][j] = f32x4{0.f, 0.f, 0.f, 0.f};
  {
    f16x8 af[4];
#pragma unroll
    for (int i = 0; i < 4; ++i)
      af[i] = *(const f16x8*)(Af1 + ((size_t)(w * 4 + i) * 64 + l) * 8);
    for (int ks = 0; ks < 8; ++ks) {
      f16x8 afn[4];
      if (ks < 7) {
#pragma unroll
        for (int i = 0; i < 4; ++i)
          afn[i] = *(const f16x8*)(Af1 + ((size_t)((ks + 1) * 16 + w * 4 + i) * 64 + l) * 8);
      }
      f16x8 bf[4];
#pragma unroll
      for (int j = 0; j < 4; ++j) {
        int n = j * 16 + lm;
        bf[j] = *(const f16x8*)(lds + n * 512 + (((ks * 4 + qq) ^ (n & 7)) * 16));
      }
#pragma unroll
      for (int i = 0; i < 4; ++i)
#pragma unroll
        for (int j = 0; j < 4; ++j)
          acc[i][j] = __builtin_amdgcn_mfma_f32_16x16x32_f16(af[i], bf[j], acc[i][j], 0, 0, 0);
#pragma unroll
      for (int i = 0; i < 4; ++i) af[i] = afn[i];
    }
  }

#pragma unroll
  for (int i = 0; i < 4; ++i) {
    const int mq = w * 64 + i * 16 + qq * 4;
    f32x4 s4 = *(const f32x4*)&bn1S[mq];
    f32x4 h4 = *(const f32x4*)&bn1H[mq];
#pragma unroll
    for (int r = 0; r < 4; ++r) {
      const int m = mq + r;
#pragma unroll
      for (int j = 0; j < 4; ++j) {
        int n = j * 16 + lm;
        out[(size_t)(b * CO + m) * Nn + n0 + n] = fmaxf(fmaf(acc[i][j][r], s4[r], h4[r]), 0.f);
      }
    }
  }
}

// ---------------------------------------------------------------- launch
extern "C" void kernel_launch(void* const* d_in, const int* in_sizes, int n_in,
                              void* d_out, int out_size, void* d_ws, size_t ws_size,
                              hipStream_t stream)
{
  const float* unknown = (const float*)d_in[0];
  const float* known   = (const float*)d_in[1];
  const float* uf      = (const float*)d_in[2];
  const float* kf      = (const float*)d_in[3];
  const float* W0  = (const float*)d_in[4];
  const float* b0  = (const float*)d_in[5];
  const float* g0  = (const float*)d_in[6];
  const float* be0 = (const float*)d_in[7];
  const float* rm0 = (const float*)d_in[8];
  const float* rv0 = (const float*)d_in[9];
  const float* W1  = (const float*)d_in[10];
  const float* b1  = (const float*)d_in[11];
  const float* g1  = (const float*)d_in[12];
  const float* be1 = (const float*)d_in[13];
  const float* rm1 = (const float*)d_in[14];
  const float* rv1 = (const float*)d_in[15];

  char* ws = (char*)d_ws;
  int*    idx = (int*)   (ws + 0);          // B*N*3 i32   = 384 KB
  float*  wts = (float*) (ws + 393216);     // B*N*3 f32   = 384 KB
  f16*    kfT = (f16*)   (ws + 786432);     // B*M*C2 f16  = 4 MB
  f16*    Af0 = (f16*)   (ws + 4980736);    // 256*384 f16 (fragment-order)
  f16*    Af1 = (f16*)   (ws + 5177344);    // 256*256 f16 (fragment-order)
  float4* k4  = (float4*)(ws + 5308416);    // B*M float4 (kx,ky,kz,kk) = 128 KB
  float*  out = (float*)d_out;              // (B,256,N) f32

  kprep_kernel<<<dim3(Bb * Mm / 256), 256, 0, stream>>>(known, k4);
  knn_kernel <<<dim3(Bb * (Nn / 64)), 512, 0, stream>>>(unknown, k4, idx, wts);
  kft_kernel <<<dim3(Mm / 64, C2 / 64, Bb), 256, 0, stream>>>(kf, kfT);
  wrep_kernel<<<dim3((CO * K0 + 255) / 256), 256, 0, stream>>>(W0, W1, Af0, Af1);
  mlp_fused  <<<dim3(Bb * (Nn / 64)), 256, 0, stream>>>(
      Af0, Af1, kfT, uf, idx, wts,
      b0, g0, be0, rm0, rv0, b1, g1, be1, rm1, rv1, out);
}

// Round 2
// 167.792 us; speedup vs baseline: 1.0163x; 1.0163x over previous
//
#include <hip/hip_runtime.h>
#include <stdint.h>
#include <stddef.h>

typedef _Float16 f16;
typedef f16 f16x4 __attribute__((ext_vector_type(4)));
typedef f16 f16x8 __attribute__((ext_vector_type(8)));
typedef float f32x4 __attribute__((ext_vector_type(4)));

#define DEV __device__ __forceinline__

constexpr int Bb = 4, Nn = 8192, Mm = 2048, C1 = 128, C2 = 256;
constexpr int K0 = 384, CO = 256;

// ---------------------------------------------------------------- 1) three_nn (np-mimic fp32)
// Block = 512 thr (8 waves) x 64 queries (one per lane). Block stages all M=2048 candidates
// as float4(kx,ky,kz,kk) in 32KB LDS (kprep fused). Each wave scans a wave-uniform 256-candidate
// slice via broadcast ds_read_b128 (uniform addr -> no bank conflicts, offsets fold to
// immediates). Ping-pong reg buffers ca/cb: consume A / refill A / consume B / refill B — no
// copy rotation, so the inner loop is a pure ~19-op VALU stream per pair.
// Per-pair math identical to verified kernel: pre-doubled query coords make dot2 == np's
// 2.0*einsum BITWISE; strict-less insertion in increasing gm + lexicographic (d,i) cross-wave
// merge reproduces numpy top_k stable tie-breaking exactly.
__global__ __launch_bounds__(512, 4) void knn_kernel(
    const float* __restrict__ unknown, const float* __restrict__ known,
    int* __restrict__ oidx, float* __restrict__ ow)
{
  __shared__ __align__(16) float4 sh[2048];          // 32 KB staged candidates
  float* mergeD = (float*)sh;                        // reused after scan: [8][64][3] f32 = 6 KB
  int*   mergeI = (int*)((char*)sh + 6144);          // [8][64][3] i32 = 6 KB

  const int t = threadIdx.x;
  const int l = t & 63;
  const int w = __builtin_amdgcn_readfirstlane(t >> 6);   // wave id 0..7 (scalar)
  const int bx = blockIdx.x;
  const int b  = bx >> 7;              // 128 blocks per batch
  const int n0 = (bx & 127) * 64;
  const int q  = n0 + l;

  // ---- stage all M candidates: 512 threads x 4 points, coalesced 12B/lane reads
#pragma unroll
  for (int j = 0; j < 4; ++j) {
    int m = t + j * 512;
    float kx = known[(b * Mm + m) * 3 + 0];
    float ky = known[(b * Mm + m) * 3 + 1];
    float kz = known[(b * Mm + m) * 3 + 2];
    float kk = __fadd_rn(__fadd_rn(__fmul_rn(kx, kx), __fmul_rn(ky, ky)), __fmul_rn(kz, kz));
    sh[m] = make_float4(kx, ky, kz, kk);
  }

  float ux = unknown[(b * Nn + q) * 3 + 0];
  float uy = unknown[(b * Nn + q) * 3 + 1];
  float uz = unknown[(b * Nn + q) * 3 + 2];
  float uu = __fadd_rn(__fadd_rn(__fmul_rn(ux, ux), __fmul_rn(uy, uy)), __fmul_rn(uz, uz));
  float ux2 = ux + ux, uy2 = uy + uy, uz2 = uz + uz;   // exact (x2 = exponent bump)

  __syncthreads();

  const float4* wb = sh + (w << 8);    // wave-uniform slice base
  const int gmb = w << 8;

  float d1 = 1e30f, d2 = 1e30f, d3 = 1e30f;
  int   i1 = 0, i2 = 0, i3 = 0;

#define STEP(kp, GM) { \
    float dot2 = __fadd_rn(__fadd_rn(__fmul_rn(ux2, (kp).x), __fmul_rn(uy2, (kp).y)), __fmul_rn(uz2, (kp).z)); \
    float dd   = __fadd_rn(__fsub_rn(uu, dot2), (kp).w); \
    bool c1 = dd < d1, c2 = dd < d2, c3 = dd < d3; \
    i3 = c3 ? (c2 ? i2 : (GM)) : i3; \
    i2 = c2 ? (c1 ? i1 : (GM)) : i2; \
    i1 = c1 ? (GM) : i1; \
    d3 = __builtin_amdgcn_fmed3f(dd, d2, d3); \
    d2 = __builtin_amdgcn_fmed3f(dd, d1, d2); \
    d1 = fminf(dd, d1); }

  float4 ca[8], cb[8];
#pragma unroll
  for (int j = 0; j < 8; ++j) ca[j] = wb[j];
#pragma unroll
  for (int j = 0; j < 8; ++j) cb[j] = wb[8 + j];

  for (int g = 0; g < 30; g += 2) {                  // groups g, g+1 in flight; prefetch g+2, g+3
#pragma unroll
    for (int j = 0; j < 8; ++j) STEP(ca[j], gmb + g * 8 + j);
#pragma unroll
    for (int j = 0; j < 8; ++j) ca[j] = wb[(g + 2) * 8 + j];
#pragma unroll
    for (int j = 0; j < 8; ++j) STEP(cb[j], gmb + (g + 1) * 8 + j);
#pragma unroll
    for (int j = 0; j < 8; ++j) cb[j] = wb[(g + 3) * 8 + j];
  }
#pragma unroll
  for (int j = 0; j < 8; ++j) STEP(ca[j], gmb + 240 + j);
#pragma unroll
  for (int j = 0; j < 8; ++j) STEP(cb[j], gmb + 248 + j);
#undef STEP

  // ---- per-wave partials -> LDS (reusing stage buffer), wave 0 merges (ties -> lower index)
  __syncthreads();                                   // scan done, sh reusable
  mergeD[(w * 64 + l) * 3 + 0] = d1; mergeD[(w * 64 + l) * 3 + 1] = d2; mergeD[(w * 64 + l) * 3 + 2] = d3;
  mergeI[(w * 64 + l) * 3 + 0] = i1; mergeI[(w * 64 + l) * 3 + 1] = i2; mergeI[(w * 64 + l) * 3 + 2] = i3;
  __syncthreads();

  if (t < 64) {
    d1 = mergeD[t * 3 + 0]; d2 = mergeD[t * 3 + 1]; d3 = mergeD[t * 3 + 2];
    i1 = mergeI[t * 3 + 0]; i2 = mergeI[t * 3 + 1]; i3 = mergeI[t * 3 + 2];
#pragma unroll
    for (int ww = 1; ww < 8; ++ww) {
#pragma unroll
      for (int u = 0; u < 3; ++u) {
        float e = mergeD[(ww * 64 + t) * 3 + u];
        int   j = mergeI[(ww * 64 + t) * 3 + u];
        bool c3 = (e < d3) || (e == d3 && j < i3);
        bool c2 = (e < d2) || (e == d2 && j < i2);
        bool c1 = (e < d1) || (e == d1 && j < i1);
        d3 = c3 ? (c2 ? d2 : e) : d3;  i3 = c3 ? (c2 ? i2 : j) : i3;
        d2 = c2 ? (c1 ? d1 : e) : d2;  i2 = c2 ? (c1 ? i1 : j) : i2;
        d1 = c1 ? e : d1;              i1 = c1 ? j : i1;
      }
    }
    float t1 = sqrtf(fmaxf(d1, 0.f)), t2 = sqrtf(fmaxf(d2, 0.f)), t3 = sqrtf(fmaxf(d3, 0.f));
    float r1 = 1.f / (t1 + 1e-8f), r2 = 1.f / (t2 + 1e-8f), r3 = 1.f / (t3 + 1e-8f);
    float rs = __fadd_rn(__fadd_rn(r1, r2), r3);
    int base = (b * Nn + n0 + t) * 3;
    oidx[base + 0] = i1; oidx[base + 1] = i2; oidx[base + 2] = i3;
    ow[base + 0] = r1 / rs; ow[base + 1] = r2 / rs; ow[base + 2] = r3 / rs;
  }
}

// ---------------------------------------------------------------- 2) fused prep: kfT transpose (z<4) + weight repack (z==4)
__global__ __launch_bounds__(256) void prep_kernel(
    const float* __restrict__ kf, f16* __restrict__ kfT,
    const float* __restrict__ W0, const float* __restrict__ W1,
    f16* __restrict__ Af0, f16* __restrict__ Af1)
{
  const int t = threadIdx.x;
  if (blockIdx.z < 4) {
    // known_feats (B,C2,M) f32 -> kfT (B,M,C2) f16
    __shared__ f16 tile[64][72];
    const int m0 = blockIdx.x * 64, c0 = blockIdx.y * 64, b = blockIdx.z;
    const int lm = t & 63, row = t >> 6;
#pragma unroll
    for (int j = 0; j < 16; ++j) {
      int c = row + j * 4;
      tile[lm][c] = (f16)kf[(size_t)(b * C2 + c0 + c) * Mm + m0 + lm];
    }
    __syncthreads();
#pragma unroll
    for (int j = 0; j < 16; ++j) {
      int m = row + j * 4;
      kfT[(size_t)(b * Mm + m0 + m) * C2 + c0 + lm] = tile[m][lm];
    }
  } else {
    // weights f32 -> f16 in MFMA A-fragment order; 128 blocks x 256 thr x 3 iters = 98304 ids
    const int bid = blockIdx.y * 32 + blockIdx.x;
#pragma unroll
    for (int r = 0; r < 3; ++r) {
      int id = bid * 256 + t + r * 32768;
      int e = id & 7, lane = (id >> 3) & 63, mg = (id >> 9) & 15, ks = id >> 13;
      int m = mg * 16 + (lane & 15), k = ks * 32 + (lane >> 4) * 8 + e;
      if (id < CO * K0) Af0[id] = (f16)W0[m * K0 + k];
      if (id < CO * CO) Af1[id] = (f16)W1[m * CO + k];
    }
  }
}

// ---------------------------------------------------------------- 3) fused interp + concat + MLP0 + MLP1 (unchanged)
__global__ __launch_bounds__(256) void mlp_fused(
    const f16* __restrict__ Af0, const f16* __restrict__ Af1,
    const f16* __restrict__ kfT, const float* __restrict__ uf,
    const int* __restrict__ idx, const float* __restrict__ wts,
    const float* __restrict__ bs0, const float* __restrict__ g0,
    const float* __restrict__ be0, const float* __restrict__ rm0, const float* __restrict__ rv0,
    const float* __restrict__ bs1, const float* __restrict__ g1,
    const float* __restrict__ be1, const float* __restrict__ rm1, const float* __restrict__ rv1,
    float* __restrict__ out)
{
  __shared__ __align__(16) char lds[53248];
  const int t = threadIdx.x;
  const int w = t >> 6, l = t & 63, lm = l & 15, qq = l >> 4;
  const int gid = blockIdx.x;
  const int b = gid >> 7, n0 = (gid & 127) * 64;

  float* bn0S = (float*)(lds + 49152);
  float* bn0H = (float*)(lds + 50176);
  float* bn1S = (float*)(lds + 51200);
  float* bn1H = (float*)(lds + 52224);
  {
    float sc0 = g0[t] / sqrtf(rv0[t] + 1e-5f);
    bn0S[t] = sc0; bn0H[t] = (bs0[t] - rm0[t]) * sc0 + be0[t];
    float sc1 = g1[t] / sqrtf(rv1[t] + 1e-5f);
    bn1S[t] = sc1; bn1H[t] = (bs1[t] - rm1[t]) * sc1 + be1[t];
  }

  {
    const int n = t >> 2, kg = t & 3;
    const int base = (b * Nn + n0 + n) * 3;
    int i0 = idx[base], i1 = idx[base + 1], i2 = idx[base + 2];
    float w0 = wts[base], w1 = wts[base + 1], w2 = wts[base + 2];
    f16 w0h = (f16)w0, w1h = (f16)w1, w2h = (f16)w2;
    f16x8 w0v = {w0h, w0h, w0h, w0h, w0h, w0h, w0h, w0h};
    f16x8 w1v = {w1h, w1h, w1h, w1h, w1h, w1h, w1h, w1h};
    f16x8 w2v = {w2h, w2h, w2h, w2h, w2h, w2h, w2h, w2h};
    const f16x8* r0 = (const f16x8*)(kfT + (size_t)(b * Mm + i0) * C2 + kg * 64);
    const f16x8* r1 = (const f16x8*)(kfT + (size_t)(b * Mm + i1) * C2 + kg * 64);
    const f16x8* r2 = (const f16x8*)(kfT + (size_t)(b * Mm + i2) * C2 + kg * 64);
#pragma unroll
    for (int j = 0; j < 8; ++j) {
      f16x8 o = r0[j] * w0v + r1[j] * w1v + r2[j] * w2v;
      int oct = kg * 8 + j;
      *(f16x8*)(lds + n * 768 + ((oct ^ (n & 7)) * 16)) = o;
    }
  }
  {
    const int n = t & 63, cb = (t >> 6) * 32;
    const float* src = uf + (size_t)(b * C1 + cb) * Nn + n0 + n;
#pragma unroll
    for (int jj = 0; jj < 4; ++jj) {
      f16x8 v;
#pragma unroll
      for (int e = 0; e < 8; ++e) v[e] = (f16)src[(size_t)(jj * 8 + e) * Nn];
      int oct = 32 + (cb >> 3) + jj;
      *(f16x8*)(lds + n * 768 + ((oct ^ (n & 7)) * 16)) = v;
    }
  }
  __syncthreads();

  f32x4 acc[4][4] = {};
  {
    f16x8 af[4];
#pragma unroll
    for (int i = 0; i < 4; ++i)
      af[i] = *(const f16x8*)(Af0 + ((size_t)(w * 4 + i) * 64 + l) * 8);
    for (int ks = 0; ks < 12; ++ks) {
      f16x8 afn[4];
      if (ks < 11) {
#pragma unroll
        for (int i = 0; i < 4; ++i)
          afn[i] = *(const f16x8*)(Af0 + ((size_t)((ks + 1) * 16 + w * 4 + i) * 64 + l) * 8);
      }
      f16x8 bf[4];
#pragma unroll
      for (int j = 0; j < 4; ++j) {
        int n = j * 16 + lm;
        bf[j] = *(const f16x8*)(lds + n * 768 + (((ks * 4 + qq) ^ (n & 7)) * 16));
      }
#pragma unroll
      for (int i = 0; i < 4; ++i)
#pragma unroll
        for (int j = 0; j < 4; ++j)
          acc[i][j] = __builtin_amdgcn_mfma_f32_16x16x32_f16(af[i], bf[j], acc[i][j], 0, 0, 0);
#pragma unroll
      for (int i = 0; i < 4; ++i) af[i] = afn[i];
    }
  }
  __syncthreads();

#pragma unroll
  for (int i = 0; i < 4; ++i) {
    const int mq = w * 64 + i * 16 + qq * 4;
    f32x4 s4 = *(const f32x4*)&bn0S[mq];
    f32x4 h4 = *(const f32x4*)&bn0H[mq];
#pragma unroll
    for (int j = 0; j < 4; ++j) {
      int n = j * 16 + lm;
      f16x4 v;
#pragma unroll
      for (int r = 0; r < 4; ++r) v[r] = (f16)fmaxf(fmaf(acc[i][j][r], s4[r], h4[r]), 0.f);
      *(f16x4*)(lds + n * 512 + (((mq >> 3) ^ (n & 7)) * 16) + (mq & 7) * 2) = v;
    }
  }
  __syncthreads();

#pragma unroll
  for (int i = 0; i < 4; ++i)
#pragma unroll
    for (int j = 0; j < 4; ++j) acc[i][j] = f32x4{0.f, 0.f, 0.f, 0.f};
  {
    f16x8 af[4];
#pragma unroll
    for (int i = 0; i < 4; ++i)
      af[i] = *(const f16x8*)(Af1 + ((size_t)(w * 4 + i) * 64 + l) * 8);
    for (int ks = 0; ks < 8; ++ks) {
      f16x8 afn[4];
      if (ks < 7) {
#pragma unroll
        for (int i = 0; i < 4; ++i)
          afn[i] = *(const f16x8*)(Af1 + ((size_t)((ks + 1) * 16 + w * 4 + i) * 64 + l) * 8);
      }
      f16x8 bf[4];
#pragma unroll
      for (int j = 0; j < 4; ++j) {
        int n = j * 16 + lm;
        bf[j] = *(const f16x8*)(lds + n * 512 + (((ks * 4 + qq) ^ (n & 7)) * 16));
      }
#pragma unroll
      for (int i = 0; i < 4; ++i)
#pragma unroll
        for (int j = 0; j < 4; ++j)
          acc[i][j] = __builtin_amdgcn_mfma_f32_16x16x32_f16(af[i], bf[j], acc[i][j], 0, 0, 0);
#pragma unroll
      for (int i = 0; i < 4; ++i) af[i] = afn[i];
    }
  }

#pragma unroll
  for (int i = 0; i < 4; ++i) {
    const int mq = w * 64 + i * 16 + qq * 4;
    f32x4 s4 = *(const f32x4*)&bn1S[mq];
    f32x4 h4 = *(const f32x4*)&bn1H[mq];
#pragma unroll
    for (int r = 0; r < 4; ++r) {
      const int m = mq + r;
#pragma unroll
      for (int j = 0; j < 4; ++j) {
        int n = j * 16 + lm;
        out[(size_t)(b * CO + m) * Nn + n0 + n] = fmaxf(fmaf(acc[i][j][r], s4[r], h4[r]), 0.f);
      }
    }
  }
}

// ---------------------------------------------------------------- launch
extern "C" void kernel_launch(void* const* d_in, const int* in_sizes, int n_in,
                              void* d_out, int out_size, void* d_ws, size_t ws_size,
                              hipStream_t stream)
{
  const float* unknown = (const float*)d_in[0];
  const float* known   = (const float*)d_in[1];
  const float* uf      = (const float*)d_in[2];
  const float* kf      = (const float*)d_in[3];
  const float* W0  = (const float*)d_in[4];
  const float* b0  = (const float*)d_in[5];
  const float* g0  = (const float*)d_in[6];
  const float* be0 = (const float*)d_in[7];
  const float* rm0 = (const float*)d_in[8];
  const float* rv0 = (const float*)d_in[9];
  const float* W1  = (const float*)d_in[10];
  const float* b1  = (const float*)d_in[11];
  const float* g1  = (const float*)d_in[12];
  const float* be1 = (const float*)d_in[13];
  const float* rm1 = (const float*)d_in[14];
  const float* rv1 = (const float*)d_in[15];

  char* ws = (char*)d_ws;
  int*    idx = (int*)   (ws + 0);          // B*N*3 i32   = 384 KB
  float*  wts = (float*) (ws + 393216);     // B*N*3 f32   = 384 KB
  f16*    kfT = (f16*)   (ws + 786432);     // B*M*C2 f16  = 4 MB
  f16*    Af0 = (f16*)   (ws + 4980736);    // 256*384 f16 (fragment-order)
  f16*    Af1 = (f16*)   (ws + 5177344);    // 256*256 f16 (fragment-order)
  float*  out = (float*)d_out;              // (B,256,N) f32

  knn_kernel <<<dim3(Bb * (Nn / 64)), 512, 0, stream>>>(unknown, known, idx, wts);
  prep_kernel<<<dim3(32, 4, 5), 256, 0, stream>>>(kf, kfT, W0, W1, Af0, Af1);
  mlp_fused  <<<dim3(Bb * (Nn / 64)), 256, 0, stream>>>(
      Af0, Af1, kfT, uf, idx, wts,
      b0, g0, be0, rm0, rv0, b1, g1, be1, rm1, rv1, out);
}

// Round 3
// 159.084 us; speedup vs baseline: 1.0720x; 1.0547x over previous
//
#include <hip/hip_runtime.h>
#include <stdint.h>
#include <stddef.h>

typedef _Float16 f16;
typedef f16 f16x4 __attribute__((ext_vector_type(4)));
typedef f16 f16x8 __attribute__((ext_vector_type(8)));
typedef float f32x4 __attribute__((ext_vector_type(4)));

#define DEV __device__ __forceinline__

constexpr int Bb = 4, Nn = 8192, Mm = 2048, C1 = 128, C2 = 256;
constexpr int K0 = 384, CO = 256;

// ---------------------------------------------------------------- 1) three_nn (np-mimic fp32)
// Structure as R2 (512 thr, 64 queries/lane-slot, wave-uniform 256-cand slice from 32KB LDS,
// broadcast ds_read_b128, cross-wave merge). NEW: the per-pair math+selection is a hand-written
// 19-instruction inline-asm STEP — measured evidence says the compiler was emitting ~43 VALU
// ops/pair (43us at 85% VALUBusy across 3 structural variants); the asm pins it at the minimum.
// Rounding chain is BITWISE the verified np-mimic: dot2 = fl(fl(fl(ux2*kx)+fl(uy2*ky))+fl(uz2*kz)),
// dd = fl(fl(uu-dot2)+kk); strict-less insert in increasing gm; (d,i)-lex merge => numpy-stable.
// Hazard note: >=4 instrs between each v_cmp and its v_cndmask consumer (gfx9 VALU->SGPR-mask
// wait states; hazard recognizer cannot see inside asm).
__global__ __launch_bounds__(512, 4) void knn_kernel(
    const float* __restrict__ unknown, const float* __restrict__ known,
    int* __restrict__ oidx, float* __restrict__ ow)
{
  __shared__ __align__(16) float4 sh[2048];          // 32 KB staged candidates
  float* mergeD = (float*)sh;                        // reused after scan: [8][64][3] f32 = 6 KB
  int*   mergeI = (int*)((char*)sh + 6144);          // [8][64][3] i32 = 6 KB

  const int t = threadIdx.x;
  const int l = t & 63;
  const int w = __builtin_amdgcn_readfirstlane(t >> 6);   // wave id 0..7 (scalar)
  const int bx = blockIdx.x;
  const int b  = bx >> 7;              // 128 blocks per batch
  const int n0 = (bx & 127) * 64;
  const int q  = n0 + l;

  // ---- stage all M candidates: 512 threads x 4 points, coalesced 12B/lane reads
#pragma unroll
  for (int j = 0; j < 4; ++j) {
    int m = t + j * 512;
    float kx = known[(b * Mm + m) * 3 + 0];
    float ky = known[(b * Mm + m) * 3 + 1];
    float kz = known[(b * Mm + m) * 3 + 2];
    float kk = __fadd_rn(__fadd_rn(__fmul_rn(kx, kx), __fmul_rn(ky, ky)), __fmul_rn(kz, kz));
    sh[m] = make_float4(kx, ky, kz, kk);
  }

  float ux = unknown[(b * Nn + q) * 3 + 0];
  float uy = unknown[(b * Nn + q) * 3 + 1];
  float uz = unknown[(b * Nn + q) * 3 + 2];
  float uu = __fadd_rn(__fadd_rn(__fmul_rn(ux, ux), __fmul_rn(uy, uy)), __fmul_rn(uz, uz));
  float ux2 = ux + ux, uy2 = uy + uy, uz2 = uz + uz;   // exact (x2 = exponent bump)

  __syncthreads();

  const float4* wb = sh + (w << 8);    // wave-uniform slice base
  const int gmb = w << 8;

  float d1 = 1e30f, d2 = 1e30f, d3 = 1e30f;
  int   i1 = 0, i2 = 0, i3 = 0;
  int   gmv = gmb;                     // running candidate index (VGPR, +1 per STEP)
  float tmp0, tmp1;
  uint64_t q1m, q2m;

  // 19-instr STEP: 7 np-exact math, 3 cmp, 3 med/min (spacing), 5 cndmask, 1 index inc.
#define STEP(kp) \
  asm( \
    "v_mul_f32 %[t], %[ux2], %[kx]\n\t" \
    "v_mul_f32 %[s], %[uy2], %[ky]\n\t" \
    "v_add_f32 %[t], %[t], %[s]\n\t" \
    "v_mul_f32 %[s], %[uz2], %[kz]\n\t" \
    "v_add_f32 %[t], %[t], %[s]\n\t" \
    "v_sub_f32 %[t], %[uu], %[t]\n\t" \
    "v_add_f32 %[t], %[t], %[kk]\n\t" \
    "v_cmp_lt_f32 %[q1], %[t], %[d1]\n\t" \
    "v_cmp_lt_f32 %[q2], %[t], %[d2]\n\t" \
    "v_cmp_lt_f32 vcc, %[t], %[d3]\n\t" \
    "v_med3_f32 %[d3], %[t], %[d2], %[d3]\n\t" \
    "v_med3_f32 %[d2], %[t], %[d1], %[d2]\n\t" \
    "v_min_f32 %[d1], %[t], %[d1]\n\t" \
    "v_cndmask_b32 %[s], %[gm], %[i2], %[q2]\n\t" \
    "v_cndmask_b32 %[i3], %[i3], %[s], vcc\n\t" \
    "v_cndmask_b32 %[s], %[gm], %[i1], %[q1]\n\t" \
    "v_cndmask_b32 %[i2], %[i2], %[s], %[q2]\n\t" \
    "v_cndmask_b32 %[i1], %[i1], %[gm], %[q1]\n\t" \
    "v_add_u32 %[gm], 1, %[gm]\n\t" \
    : [d1]"+v"(d1), [d2]"+v"(d2), [d3]"+v"(d3), \
      [i1]"+v"(i1), [i2]"+v"(i2), [i3]"+v"(i3), \
      [gm]"+v"(gmv), [t]"=&v"(tmp0), [s]"=&v"(tmp1), \
      [q1]"=&s"(q1m), [q2]"=&s"(q2m) \
    : [ux2]"v"(ux2), [uy2]"v"(uy2), [uz2]"v"(uz2), [uu]"v"(uu), \
      [kx]"v"((kp).x), [ky]"v"((kp).y), [kz]"v"((kp).z), [kk]"v"((kp).w) \
    : "vcc")

  float4 ca[4], cb[4];
#pragma unroll
  for (int j = 0; j < 4; ++j) ca[j] = wb[j];
#pragma unroll
  for (int j = 0; j < 4; ++j) cb[j] = wb[4 + j];

  for (int g = 0; g < 31; ++g) {                 // 8 candidates/iter; refill one group ahead
#pragma unroll
    for (int j = 0; j < 4; ++j) STEP(ca[j]);
#pragma unroll
    for (int j = 0; j < 4; ++j) ca[j] = wb[(g + 1) * 8 + j];
#pragma unroll
    for (int j = 0; j < 4; ++j) STEP(cb[j]);
#pragma unroll
    for (int j = 0; j < 4; ++j) cb[j] = wb[(g + 1) * 8 + 4 + j];
  }
#pragma unroll
  for (int j = 0; j < 4; ++j) STEP(ca[j]);
#pragma unroll
  for (int j = 0; j < 4; ++j) STEP(cb[j]);
#undef STEP

  // ---- per-wave partials -> LDS (reusing stage buffer), wave 0 merges (ties -> lower index)
  __syncthreads();                                   // scan done, sh reusable
  mergeD[(w * 64 + l) * 3 + 0] = d1; mergeD[(w * 64 + l) * 3 + 1] = d2; mergeD[(w * 64 + l) * 3 + 2] = d3;
  mergeI[(w * 64 + l) * 3 + 0] = i1; mergeI[(w * 64 + l) * 3 + 1] = i2; mergeI[(w * 64 + l) * 3 + 2] = i3;
  __syncthreads();

  if (t < 64) {
    d1 = mergeD[t * 3 + 0]; d2 = mergeD[t * 3 + 1]; d3 = mergeD[t * 3 + 2];
    i1 = mergeI[t * 3 + 0]; i2 = mergeI[t * 3 + 1]; i3 = mergeI[t * 3 + 2];
#pragma unroll
    for (int ww = 1; ww < 8; ++ww) {
#pragma unroll
      for (int u = 0; u < 3; ++u) {
        float e = mergeD[(ww * 64 + t) * 3 + u];
        int   j = mergeI[(ww * 64 + t) * 3 + u];
        bool c3 = (e < d3) || (e == d3 && j < i3);
        bool c2 = (e < d2) || (e == d2 && j < i2);
        bool c1 = (e < d1) || (e == d1 && j < i1);
        d3 = c3 ? (c2 ? d2 : e) : d3;  i3 = c3 ? (c2 ? i2 : j) : i3;
        d2 = c2 ? (c1 ? d1 : e) : d2;  i2 = c2 ? (c1 ? i1 : j) : i2;
        d1 = c1 ? e : d1;              i1 = c1 ? j : i1;
      }
    }
    float t1 = sqrtf(fmaxf(d1, 0.f)), t2 = sqrtf(fmaxf(d2, 0.f)), t3 = sqrtf(fmaxf(d3, 0.f));
    float r1 = 1.f / (t1 + 1e-8f), r2 = 1.f / (t2 + 1e-8f), r3 = 1.f / (t3 + 1e-8f);
    float rs = __fadd_rn(__fadd_rn(r1, r2), r3);
    int base = (b * Nn + n0 + t) * 3;
    oidx[base + 0] = i1; oidx[base + 1] = i2; oidx[base + 2] = i3;
    ow[base + 0] = r1 / rs; ow[base + 1] = r2 / rs; ow[base + 2] = r3 / rs;
  }
}

// ---------------------------------------------------------------- 2) fused prep: kfT transpose (z<4) + weight repack (z==4)
__global__ __launch_bounds__(256) void prep_kernel(
    const float* __restrict__ kf, f16* __restrict__ kfT,
    const float* __restrict__ W0, const float* __restrict__ W1,
    f16* __restrict__ Af0, f16* __restrict__ Af1)
{
  const int t = threadIdx.x;
  if (blockIdx.z < 4) {
    // known_feats (B,C2,M) f32 -> kfT (B,M,C2) f16
    __shared__ f16 tile[64][72];
    const int m0 = blockIdx.x * 64, c0 = blockIdx.y * 64, b = blockIdx.z;
    const int lm = t & 63, row = t >> 6;
#pragma unroll
    for (int j = 0; j < 16; ++j) {
      int c = row + j * 4;
      tile[lm][c] = (f16)kf[(size_t)(b * C2 + c0 + c) * Mm + m0 + lm];
    }
    __syncthreads();
#pragma unroll
    for (int j = 0; j < 16; ++j) {
      int m = row + j * 4;
      kfT[(size_t)(b * Mm + m0 + m) * C2 + c0 + lm] = tile[m][lm];
    }
  } else {
    // weights f32 -> f16 in MFMA A-fragment order; 128 blocks x 256 thr x 3 iters = 98304 ids
    const int bid = blockIdx.y * 32 + blockIdx.x;
#pragma unroll
    for (int r = 0; r < 3; ++r) {
      int id = bid * 256 + t + r * 32768;
      int e = id & 7, lane = (id >> 3) & 63, mg = (id >> 9) & 15, ks = id >> 13;
      int m = mg * 16 + (lane & 15), k = ks * 32 + (lane >> 4) * 8 + e;
      if (id < CO * K0) Af0[id] = (f16)W0[m * K0 + k];
      if (id < CO * CO) Af1[id] = (f16)W1[m * CO + k];
    }
  }
}

// ---------------------------------------------------------------- 3) fused interp + concat + MLP0 + MLP1 (unchanged)
__global__ __launch_bounds__(256) void mlp_fused(
    const f16* __restrict__ Af0, const f16* __restrict__ Af1,
    const f16* __restrict__ kfT, const float* __restrict__ uf,
    const int* __restrict__ idx, const float* __restrict__ wts,
    const float* __restrict__ bs0, const float* __restrict__ g0,
    const float* __restrict__ be0, const float* __restrict__ rm0, const float* __restrict__ rv0,
    const float* __restrict__ bs1, const float* __restrict__ g1,
    const float* __restrict__ be1, const float* __restrict__ rm1, const float* __restrict__ rv1,
    float* __restrict__ out)
{
  __shared__ __align__(16) char lds[53248];
  const int t = threadIdx.x;
  const int w = t >> 6, l = t & 63, lm = l & 15, qq = l >> 4;
  const int gid = blockIdx.x;
  const int b = gid >> 7, n0 = (gid & 127) * 64;

  float* bn0S = (float*)(lds + 49152);
  float* bn0H = (float*)(lds + 50176);
  float* bn1S = (float*)(lds + 51200);
  float* bn1H = (float*)(lds + 52224);
  {
    float sc0 = g0[t] / sqrtf(rv0[t] + 1e-5f);
    bn0S[t] = sc0; bn0H[t] = (bs0[t] - rm0[t]) * sc0 + be0[t];
    float sc1 = g1[t] / sqrtf(rv1[t] + 1e-5f);
    bn1S[t] = sc1; bn1H[t] = (bs1[t] - rm1[t]) * sc1 + be1[t];
  }

  {
    const int n = t >> 2, kg = t & 3;
    const int base = (b * Nn + n0 + n) * 3;
    int i0 = idx[base], i1 = idx[base + 1], i2 = idx[base + 2];
    float w0 = wts[base], w1 = wts[base + 1], w2 = wts[base + 2];
    f16 w0h = (f16)w0, w1h = (f16)w1, w2h = (f16)w2;
    f16x8 w0v = {w0h, w0h, w0h, w0h, w0h, w0h, w0h, w0h};
    f16x8 w1v = {w1h, w1h, w1h, w1h, w1h, w1h, w1h, w1h};
    f16x8 w2v = {w2h, w2h, w2h, w2h, w2h, w2h, w2h, w2h};
    const f16x8* r0 = (const f16x8*)(kfT + (size_t)(b * Mm + i0) * C2 + kg * 64);
    const f16x8* r1 = (const f16x8*)(kfT + (size_t)(b * Mm + i1) * C2 + kg * 64);
    const f16x8* r2 = (const f16x8*)(kfT + (size_t)(b * Mm + i2) * C2 + kg * 64);
#pragma unroll
    for (int j = 0; j < 8; ++j) {
      f16x8 o = r0[j] * w0v + r1[j] * w1v + r2[j] * w2v;
      int oct = kg * 8 + j;
      *(f16x8*)(lds + n * 768 + ((oct ^ (n & 7)) * 16)) = o;
    }
  }
  {
    const int n = t & 63, cb = (t >> 6) * 32;
    const float* src = uf + (size_t)(b * C1 + cb) * Nn + n0 + n;
#pragma unroll
    for (int jj = 0; jj < 4; ++jj) {
      f16x8 v;
#pragma unroll
      for (int e = 0; e < 8; ++e) v[e] = (f16)src[(size_t)(jj * 8 + e) * Nn];
      int oct = 32 + (cb >> 3) + jj;
      *(f16x8*)(lds + n * 768 + ((oct ^ (n & 7)) * 16)) = v;
    }
  }
  __syncthreads();

  f32x4 acc[4][4] = {};
  {
    f16x8 af[4];
#pragma unroll
    for (int i = 0; i < 4; ++i)
      af[i] = *(const f16x8*)(Af0 + ((size_t)(w * 4 + i) * 64 + l) * 8);
    for (int ks = 0; ks < 12; ++ks) {
      f16x8 afn[4];
      if (ks < 11) {
#pragma unroll
        for (int i = 0; i < 4; ++i)
          afn[i] = *(const f16x8*)(Af0 + ((size_t)((ks + 1) * 16 + w * 4 + i) * 64 + l) * 8);
      }
      f16x8 bf[4];
#pragma unroll
      for (int j = 0; j < 4; ++j) {
        int n = j * 16 + lm;
        bf[j] = *(const f16x8*)(lds + n * 768 + (((ks * 4 + qq) ^ (n & 7)) * 16));
      }
#pragma unroll
      for (int i = 0; i < 4; ++i)
#pragma unroll
        for (int j = 0; j < 4; ++j)
          acc[i][j] = __builtin_amdgcn_mfma_f32_16x16x32_f16(af[i], bf[j], acc[i][j], 0, 0, 0);
#pragma unroll
      for (int i = 0; i < 4; ++i) af[i] = afn[i];
    }
  }
  __syncthreads();

#pragma unroll
  for (int i = 0; i < 4; ++i) {
    const int mq = w * 64 + i * 16 + qq * 4;
    f32x4 s4 = *(const f32x4*)&bn0S[mq];
    f32x4 h4 = *(const f32x4*)&bn0H[mq];
#pragma unroll
    for (int j = 0; j < 4; ++j) {
      int n = j * 16 + lm;
      f16x4 v;
#pragma unroll
      for (int r = 0; r < 4; ++r) v[r] = (f16)fmaxf(fmaf(acc[i][j][r], s4[r], h4[r]), 0.f);
      *(f16x4*)(lds + n * 512 + (((mq >> 3) ^ (n & 7)) * 16) + (mq & 7) * 2) = v;
    }
  }
  __syncthreads();

#pragma unroll
  for (int i = 0; i < 4; ++i)
#pragma unroll
    for (int j = 0; j < 4; ++j) acc[i][j] = f32x4{0.f, 0.f, 0.f, 0.f};
  {
    f16x8 af[4];
#pragma unroll
    for (int i = 0; i < 4; ++i)
      af[i] = *(const f16x8*)(Af1 + ((size_t)(w * 4 + i) * 64 + l) * 8);
    for (int ks = 0; ks < 8; ++ks) {
      f16x8 afn[4];
      if (ks < 7) {
#pragma unroll
        for (int i = 0; i < 4; ++i)
          afn[i] = *(const f16x8*)(Af1 + ((size_t)((ks + 1) * 16 + w * 4 + i) * 64 + l) * 8);
      }
      f16x8 bf[4];
#pragma unroll
      for (int j = 0; j < 4; ++j) {
        int n = j * 16 + lm;
        bf[j] = *(const f16x8*)(lds + n * 512 + (((ks * 4 + qq) ^ (n & 7)) * 16));
      }
#pragma unroll
      for (int i = 0; i < 4; ++i)
#pragma unroll
        for (int j = 0; j < 4; ++j)
          acc[i][j] = __builtin_amdgcn_mfma_f32_16x16x32_f16(af[i], bf[j], acc[i][j], 0, 0, 0);
#pragma unroll
      for (int i = 0; i < 4; ++i) af[i] = afn[i];
    }
  }

#pragma unroll
  for (int i = 0; i < 4; ++i) {
    const int mq = w * 64 + i * 16 + qq * 4;
    f32x4 s4 = *(const f32x4*)&bn1S[mq];
    f32x4 h4 = *(const f32x4*)&bn1H[mq];
#pragma unroll
    for (int r = 0; r < 4; ++r) {
      const int m = mq + r;
#pragma unroll
      for (int j = 0; j < 4; ++j) {
        int n = j * 16 + lm;
        out[(size_t)(b * CO + m) * Nn + n0 + n] = fmaxf(fmaf(acc[i][j][r], s4[r], h4[r]), 0.f);
      }
    }
  }
}

// ---------------------------------------------------------------- launch
extern "C" void kernel_launch(void* const* d_in, const int* in_sizes, int n_in,
                              void* d_out, int out_size, void* d_ws, size_t ws_size,
                              hipStream_t stream)
{
  const float* unknown = (const float*)d_in[0];
  const float* known   = (const float*)d_in[1];
  const float* uf      = (const float*)d_in[2];
  const float* kf      = (const float*)d_in[3];
  const float* W0  = (const float*)d_in[4];
  const float* b0  = (const float*)d_in[5];
  const float* g0  = (const float*)d_in[6];
  const float* be0 = (const float*)d_in[7];
  const float* rm0 = (const float*)d_in[8];
  const float* rv0 = (const float*)d_in[9];
  const float* W1  = (const float*)d_in[10];
  const float* b1  = (const float*)d_in[11];
  const float* g1  = (const float*)d_in[12];
  const float* be1 = (const float*)d_in[13];
  const float* rm1 = (const float*)d_in[14];
  const float* rv1 = (const float*)d_in[15];

  char* ws = (char*)d_ws;
  int*    idx = (int*)   (ws + 0);          // B*N*3 i32   = 384 KB
  float*  wts = (float*) (ws + 393216);     // B*N*3 f32   = 384 KB
  f16*    kfT = (f16*)   (ws + 786432);     // B*M*C2 f16  = 4 MB
  f16*    Af0 = (f16*)   (ws + 4980736);    // 256*384 f16 (fragment-order)
  f16*    Af1 = (f16*)   (ws + 5177344);    // 256*256 f16 (fragment-order)
  float*  out = (float*)d_out;              // (B,256,N) f32

  knn_kernel <<<dim3(Bb * (Nn / 64)), 512, 0, stream>>>(unknown, known, idx, wts);
  prep_kernel<<<dim3(32, 4, 5), 256, 0, stream>>>(kf, kfT, W0, W1, Af0, Af1);
  mlp_fused  <<<dim3(Bb * (Nn / 64)), 256, 0, stream>>>(
      Af0, Af1, kfT, uf, idx, wts,
      b0, g0, be0, rm0, rv0, b1, g1, be1, rm1, rv1, out);
}